// Round 9
// baseline (385.521 us; speedup 1.0000x reference)
//
#include <hip/hip_runtime.h>

// ---------------------------------------------------------------------------
// MultiHeadAttention (softmax over QUERY axis) — MI355X / gfx950, bf16 MFMA.
// B=4, S=2048, D=1024, H=16, Dk=64. Inputs/outputs fp32.
// attn[i,j] = exp(s_ij)/L_j, L_j = sum_i exp(s_ij)   (column softmax)
//
// ws (64 MiB): Qb@0 | Kb@16MiB | Vb@32MiB | Xb@48MiB  (bf16 [B,H,S,Dk]/[B,S,D])
// d_out scratch until final GEMM: Lg@+0 (512KiB) | WtQ/WtK/WtV bf16 @+1MiB.
// WtO transposed into ws@0 (Qb region, dead after attn_pv).
//
// ROUND-14: GEMMs -> counted-vmcnt pipeline (T3/T4, m218 mechanism).  r12/r13
// showed both drain-per-iter structures stuck ~6x off floor (MfmaUtil 17,
// everything idle).  gemm_pipe: BK=32, THREE LDS buffers (48KB -> 3 blk/CU),
// depth-2 prefetch, K-loop FULLY UNROLLED (static buf/parity idx, rule #20),
// barrier = asm "s_waitcnt vmcnt(6|4) lgkmcnt(0)" + s_barrier (never
// vmcnt(0): this iter's 6 stage-ops stay in flight across the barrier;
// tile t+1's ops -- issued one iter earlier -- are forced complete).
// fp32-A: load->regs at t (for tile t+2), cvt+ds_write at t+1 (T14).
// colsum / attn_pv / wtrans unchanged from r13.
// ---------------------------------------------------------------------------

#define B_   4
#define S_   2048
#define D_   1024
#define H_   16
#define DK_  64
#define BH_  64
#define SC2_    0.18033688f   // 0.125 * log2(e), folded into Q projection

typedef __bf16 bf16x2 __attribute__((ext_vector_type(2)));
typedef __bf16 bf16x4 __attribute__((ext_vector_type(4)));
typedef __bf16 bf16x8 __attribute__((ext_vector_type(8)));
typedef float  f32x4  __attribute__((ext_vector_type(4)));
typedef unsigned int u32;

#define MFMA16(a,b,c) __builtin_amdgcn_mfma_f32_16x16x32_bf16((a),(b),(c),0,0,0)

__device__ __forceinline__ bf16x8 ld8(const __bf16* p){ return *(const bf16x8*)p; }

// async global->LDS, 16B per lane; LDS dest = wave-uniform base + lane*16
__device__ __forceinline__ void gll16(const __bf16* g, __bf16* l) {
    __builtin_amdgcn_global_load_lds(
        (const __attribute__((address_space(1))) u32*)g,
        (__attribute__((address_space(3))) u32*)l, 16, 0, 0);
}

// counted-vmcnt barrier: leave N newest VMEM ops in flight across the barrier
#define PIPE_BAR(N) do {                                                      \
    asm volatile("s_waitcnt vmcnt(" #N ") lgkmcnt(0)" ::: "memory");          \
    __builtin_amdgcn_s_barrier();                                             \
    __builtin_amdgcn_sched_barrier(0);                                        \
} while (0)

// ---------------------------------------------------------------------------
// wtrans3: W [k][n] fp32 -> Wt [n][k] bf16, 3 matrices (blockIdx.z selects).
// ---------------------------------------------------------------------------
__global__ __launch_bounds__(256) void wtrans3(
    const float* __restrict__ W0, const float* __restrict__ W1,
    const float* __restrict__ W2, __bf16* __restrict__ Wt)
{
    __shared__ __align__(16) __bf16 Ls[64][80];
    const int t = threadIdx.x;
    const int k0 = blockIdx.x * 64, n0 = blockIdx.y * 64, z = blockIdx.z;
    const float* W = (z == 0) ? W0 : ((z == 1) ? W1 : W2);
    __bf16* out = Wt + (size_t)z * D_ * D_;

#pragma unroll
    for (int p = 0; p < 4; ++p) {               // 1024 tasks: 64 k x 16 n-quads
        int id = p*256 + t;
        int k = id >> 4, nq = id & 15;
        f32x4 v = *(const f32x4*)&W[(size_t)(k0 + k)*D_ + n0 + nq*4];
#pragma unroll
        for (int u = 0; u < 4; ++u) Ls[nq*4 + u][k] = (__bf16)v[u];
    }
    __syncthreads();
#pragma unroll
    for (int p = 0; p < 2; ++p) {               // 512 tasks: 64 n x 8 chunks
        int id = p*256 + t;
        int n = id >> 3, c = id & 7;
        *(bf16x8*)&out[(size_t)(n0 + n)*D_ + k0 + c*8] =
            *(const bf16x8*)&Ls[n][c*8];
    }
}

// ---------------------------------------------------------------------------
// gemm_pipe: counted-vmcnt pipelined GEMM body.
//   C[m][n] = (sum_k A[m][k]*Wt[n][k] + bias[n]) * scale   (Wt = W^T bf16)
//   128x128 tile, BK=32, 3 LDS buffers (48 KB), depth-2 prefetch, fully
//   unrolled 32-iter K-loop.  4 waves (2x2, 64x64), 16 MFMA/iter.
//   Swizzle (r3-verified, 32-elem rows): phys chunk c holds logical
//   c^(row&3); read at phys fq^(row&3).
//   ABF16=1: A via gll16 (4 gll16/iter total), barrier vmcnt(4).
//   ABF16=0: A fp32 reg-load at t (tile t+2), cvt+ds_write at t+1 (named
//   reg double-buffer xa0/xa1), B via gll16; barrier vmcnt(6).
//   MODE 0: C fp32 [8192][1024]; MODE 1: C bf16 scatter [B,H,S,Dk].
// ---------------------------------------------------------------------------
template<int ABF16, int MODE>
__device__ __forceinline__ void gemm_pipe(
    const void* __restrict__ Ap, const __bf16* __restrict__ Wt,
    const float* __restrict__ bias, void* __restrict__ C,
    float scale, int m0, int n0)
{
    __shared__ __align__(16) __bf16 As[3][128*32];   // 8 KB x3
    __shared__ __align__(16) __bf16 Bs[3][128*32];   // 8 KB x3

    const int t = threadIdx.x, lane = t & 63, w = t >> 6;
    const int wm = w >> 1, wn = w & 1;
    const int fr = lane & 15, fq = lane >> 4;

    const __bf16* Ab = (const __bf16*)Ap;
    const float*  Af = (const float*)Ap;

    f32x4 acc[4][4];
#pragma unroll
    for (int i = 0; i < 4; ++i)
#pragma unroll
        for (int j = 0; j < 4; ++j) acc[i][j] = (f32x4){0.f,0.f,0.f,0.f};

    // 512 16B-chunks per tile; id = p*256+t, row = id>>2, phys chunk id&3
    // holds logical (id&3)^(row&3); LDS linear at id*16B.
#define PSTAGE_B(kk, bsel)                                                    \
    _Pragma("unroll")                                                         \
    for (int p = 0; p < 2; ++p) {                                             \
        int id = p*256 + t;                                                   \
        int n = id >> 2, l = (id & 3) ^ (n & 3);                              \
        gll16(&Wt[(size_t)(n0 + n)*D_ + (kk) + l*8],                          \
              &Bs[bsel][(size_t)(p*256 + (t & ~63))*8]);                      \
    }

#define PSTAGE_A_BF(kk, bsel)                                                 \
    _Pragma("unroll")                                                         \
    for (int p = 0; p < 2; ++p) {                                             \
        int id = p*256 + t;                                                   \
        int row = id >> 2, l = (id & 3) ^ (row & 3);                          \
        gll16(&Ab[(size_t)(m0 + row)*D_ + (kk) + l*8],                        \
              &As[bsel][(size_t)(p*256 + (t & ~63))*8]);                      \
    }

#define PLOAD_A(kk, xa)                                                       \
    _Pragma("unroll")                                                         \
    for (int p = 0; p < 2; ++p) {                                             \
        int id = p*256 + t;                                                   \
        int row = id >> 2, l = (id & 3) ^ (row & 3);                          \
        const float* ap = &Af[(size_t)(m0 + row)*D_ + (kk) + l*8];            \
        xa[2*p]   = *(const f32x4*)ap;                                        \
        xa[2*p+1] = *(const f32x4*)(ap + 4);                                  \
    }

#define PCVT_WR(xa, bsel)                                                     \
    _Pragma("unroll")                                                         \
    for (int p = 0; p < 2; ++p) {                                             \
        f32x4 x0 = xa[2*p], x1 = xa[2*p+1];                                   \
        bf16x8 v = { (__bf16)x0[0], (__bf16)x0[1], (__bf16)x0[2],             \
                     (__bf16)x0[3], (__bf16)x1[0], (__bf16)x1[1],             \
                     (__bf16)x1[2], (__bf16)x1[3] };                          \
        *(bf16x8*)&As[bsel][(size_t)(p*256 + t)*8] = v;                       \
    }

    f32x4 xa0[4], xa1[4];   // named A-reg double buffer (fp32 path only)

    // ---- prologue: prefetch tiles 0 and 1 ----
    if (ABF16) {
        PSTAGE_A_BF(0, 0)  PSTAGE_B(0, 0)     // 4 ops (tile 0)
        PSTAGE_A_BF(32, 1) PSTAGE_B(32, 1)    // 4 ops (tile 1)
        PIPE_BAR(4);                           // tile 0 done, tile 1 in flight
    } else {
        PSTAGE_B(0, 0)  PLOAD_A(0, xa0)       // 6 ops (tile 0)
        PSTAGE_B(32, 1) PLOAD_A(32, xa1)      // 6 ops (tile 1)
        PCVT_WR(xa0, 0)                        // compiler waits vmcnt<=6
        PIPE_BAR(6);                           // tile 1's 6 stay in flight
    }

    // ---- main loop: 32 iters, fully unrolled (static %3 and parity) ----
#pragma unroll
    for (int tt = 0; tt < 32; ++tt) {
        const int cur = tt % 3, nx1 = (tt + 1) % 3, nx2 = (tt + 2) % 3;

        if (ABF16) {
            if (tt < 30) {
                PSTAGE_A_BF(32*(tt + 2), nx2)
                PSTAGE_B(32*(tt + 2), nx2)
            }
        } else {
            if (tt < 30) {
                PSTAGE_B(32*(tt + 2), nx2)
                if (tt & 1) { PLOAD_A(32*(tt + 2), xa1) }
                else        { PLOAD_A(32*(tt + 2), xa0) }
            }
            if (tt < 31) {   // cvt+write tile t+1 (loaded at t-1 / prologue)
                if (tt & 1) { PCVT_WR(xa0, nx1) }
                else        { PCVT_WR(xa1, nx1) }
            }
        }

        // 16 MFMA from buffer cur (staged >=2 barriers ago)
        {
            bf16x8 af[4], bfr[4];
#pragma unroll
            for (int mt = 0; mt < 4; ++mt) {
                int row = wm*64 + mt*16 + fr;
                af[mt] = ld8(&As[cur][row*32 + 8*(fq ^ (row & 3))]);
            }
#pragma unroll
            for (int nt = 0; nt < 4; ++nt) {
                int n = wn*64 + nt*16 + fr;
                bfr[nt] = ld8(&Bs[cur][n*32 + 8*(fq ^ (n & 3))]);
            }
#pragma unroll
            for (int mt = 0; mt < 4; ++mt)
#pragma unroll
                for (int nt = 0; nt < 4; ++nt)
                    acc[mt][nt] = MFMA16(af[mt], bfr[nt], acc[mt][nt]);
        }

        if (ABF16) { PIPE_BAR(4); } else { PIPE_BAR(6); }
    }
#undef PSTAGE_B
#undef PSTAGE_A_BF
#undef PLOAD_A
#undef PCVT_WR

#pragma unroll
    for (int mt = 0; mt < 4; ++mt)
#pragma unroll
        for (int nt = 0; nt < 4; ++nt) {
            int colg = n0 + wn*64 + nt*16 + fr;
            float bv = bias[colg];
#pragma unroll
            for (int r = 0; r < 4; ++r) {
                int rowg = m0 + wm*64 + mt*16 + fq*4 + r;
                float o = (acc[mt][nt][r] + bv) * scale;
                if (MODE == 0) {
                    ((float*)C)[(size_t)rowg*D_ + colg] = o;
                } else {
                    int b = rowg >> 11, sp = rowg & (S_-1);
                    int h = colg >> 6, dk = colg & 63;
                    ((__bf16*)C)[(((size_t)(b*H_ + h))*S_ + sp)*DK_ + dk] = (__bf16)o;
                }
            }
        }
}

// single-GEMM wrapper (final output GEMM); 1D grid 512: m = gid&63
template<int ABF16, int MODE>
__global__ __launch_bounds__(256) void gemm128(
    const void* __restrict__ Ap, const __bf16* __restrict__ Wt,
    const float* __restrict__ bias, void* __restrict__ C, float scale)
{
    const int gid = blockIdx.x;
    gemm_pipe<ABF16, MODE>(Ap, Wt, bias, C, scale,
                           (gid & 63) * 128, ((gid >> 6) & 7) * 128);
}

// batched Q/K/V projection: 1536 blocks, z = gid>>9 selects the sub-GEMM.
__global__ __launch_bounds__(256) void gemm_proj3(
    const float* __restrict__ q, const float* __restrict__ k,
    const float* __restrict__ v, const __bf16* __restrict__ Wt3,
    const float* __restrict__ bq, const float* __restrict__ bk,
    const float* __restrict__ bv,
    __bf16* __restrict__ Qb, __bf16* __restrict__ Kb, __bf16* __restrict__ Vb)
{
    const int gid = blockIdx.x;
    const int z = gid >> 9, inner = gid & 511;
    const float*  A    = (z == 0) ? q  : ((z == 1) ? k  : v);
    const __bf16* Wt   = Wt3 + (size_t)z * D_ * D_;
    const float*  bias = (z == 0) ? bq : ((z == 1) ? bk : bv);
    __bf16*       C    = (z == 0) ? Qb : ((z == 1) ? Kb : Vb);
    const float scale  = (z == 0) ? SC2_ : 1.0f;
    gemm_pipe<0, 1>(A, Wt, bias, C, scale,
                    (inner & 63) * 128, (inner >> 6) * 128);
}

// ---------------------------------------------------------------------------
// Column-softmax log-sums: Lg[bh][j] = -log2( sum_i exp2(s_ij) ).
//   2048 blocks (1D, bh = gid&63 -> XCD-local Q), 4 waves x 16 j each.
// ---------------------------------------------------------------------------
__global__ __launch_bounds__(256) void colsum_rcp(
    const __bf16* __restrict__ Q, const __bf16* __restrict__ K,
    float* __restrict__ Lg)
{
    __shared__ __align__(16) __bf16 Qs[2][64*64];   // 16 KB
    const int t = threadIdx.x, lane = t & 63, w = t >> 6;
    const int fr = lane & 15, fq = lane >> 4;
    const int gid = blockIdx.x;
    const int bh = gid & 63;
    const int jw = (gid >> 6)*64 + w*16;            // wave's 16 j
    const __bf16* Qb = Q + (size_t)bh*S_*DK_;
    const __bf16* Kb = K + (size_t)bh*S_*DK_;

    bf16x8 kh0, kh1;
    {
        const __bf16* kr = &Kb[(size_t)(jw + fr)*DK_];
        kh0 = ld8(kr + fq*8);
        kh1 = ld8(kr + 32 + fq*8);
    }

    float accl[4] = {};

#pragma unroll
    for (int p = 0; p < 2; ++p) {
        int c = p*256 + t;
        int i = c >> 3, l = (c & 7) ^ (i & 7);
        gll16(&Qb[(size_t)i*DK_ + l*8], &Qs[0][(size_t)(p*256 + (t & ~63))*8]);
    }
    __syncthreads();

    for (int i0 = 0; i0 < S_; i0 += 64) {
        const int cur = (i0 >> 6) & 1;
        if (i0 + 64 < S_) {
#pragma unroll
            for (int p = 0; p < 2; ++p) {
                int c = p*256 + t;
                int i = c >> 3, l = (c & 7) ^ (i & 7);
                gll16(&Qb[(size_t)(i0 + 64 + i)*DK_ + l*8],
                      &Qs[cur ^ 1][(size_t)(p*256 + (t & ~63))*8]);
            }
        }
#pragma unroll
        for (int it = 0; it < 4; ++it) {
            int i = it*16 + fr;
            bf16x8 q0 = ld8(&Qs[cur][i*64 + 8*(fq ^ (i & 7))]);
            bf16x8 q1 = ld8(&Qs[cur][i*64 + 8*((4 + fq) ^ (i & 7))]);
            f32x4 s = MFMA16(kh0, q0, ((f32x4){0.f,0.f,0.f,0.f}));
            s = MFMA16(kh1, q1, s);
#pragma unroll
            for (int r = 0; r < 4; ++r)
                accl[r] += __builtin_amdgcn_exp2f(s[r]);
        }
        __syncthreads();
    }
#pragma unroll
    for (int r = 0; r < 4; ++r) {
        accl[r] += __shfl_xor(accl[r], 1, 64);
        accl[r] += __shfl_xor(accl[r], 2, 64);
        accl[r] += __shfl_xor(accl[r], 4, 64);
        accl[r] += __shfl_xor(accl[r], 8, 64);
    }
    if (fr == 0) {
#pragma unroll
        for (int r = 0; r < 4; ++r)
            Lg[(size_t)bh*S_ + jw + fq*4 + r] = -__log2f(accl[r]);
    }
}

// ---------------------------------------------------------------------------
// Pass 2: X[i,:] = sum_j exp2(s_ij + Lg_j) * V[j,:]   (s pre-scaled by SC2)
// ---------------------------------------------------------------------------
__global__ __launch_bounds__(512, 4) void attn_pv(
    const __bf16* __restrict__ Q, const __bf16* __restrict__ K,
    const __bf16* __restrict__ V, const float* __restrict__ Lg,
    __bf16* __restrict__ X)
{
    __shared__ __align__(16) __bf16 Ks[2][64*64];   // 16 KB
    __shared__ __align__(16) __bf16 Vs[2][64*64];   // 16 KB
    __shared__ __align__(16) __bf16 Pl[8][32*64];   // 32 KB

    const int t = threadIdx.x, lane = t & 63, w = t >> 6;
    const int fr = lane & 15, fq = lane >> 4;
    const int gid = blockIdx.x;
    const int bh = gid & 63;
    const int iw = (gid >> 6)*256 + w*32;           // wave's i base
    const __bf16* Qb = Q + (size_t)bh*S_*DK_;
    const __bf16* Kb = K + (size_t)bh*S_*DK_;
    const __bf16* Vb = V + (size_t)bh*S_*DK_;
    const float*  Rb = Lg + (size_t)bh*S_;

    bf16x8 qf[2][2];
#pragma unroll
    for (int it = 0; it < 2; ++it)
#pragma unroll
        for (int kf = 0; kf < 2; ++kf)
            qf[it][kf] = ld8(&Qb[(size_t)(iw + it*16 + fr)*DK_ + kf*32 + fq*8]);

    const int dq = t & 15, jp = t >> 4;
    const int krow = t >> 3;
    const int kchk = (t & 7) ^ (krow & 7);

    f32x4 acc[2][4];
#pragma unroll
    for (int it = 0; it < 2; ++it)
#pragma unroll
        for (int dt = 0; dt < 4; ++dt) acc[it][dt] = (f32x4){0.f,0.f,0.f,0.f};

    gll16(&Kb[(size_t)krow*DK_ + kchk*8], &Ks[0][(t & ~63)*8]);
    __syncthreads();

    for (int jg = 0; jg < S_; jg += 64) {
        const int cur = (jg >> 6) & 1;

        bf16x4 v0 = *(const bf16x4*)&Vb[(size_t)(jg + 2*jp    )*DK_ + dq*4];
        bf16x4 v1 = *(const bf16x4*)&Vb[(size_t)(jg + 2*jp + 1)*DK_ + dq*4];
        f32x4 lg[4];
#pragma unroll
        for (int jt = 0; jt < 4; ++jt)
            lg[jt] = *(const f32x4*)&Rb[jg + jt*16 + fq*4];
        if (jg + 64 < S_)
            gll16(&Kb[(size_t)(jg + 64 + krow)*DK_ + kchk*8],
                  &Ks[cur ^ 1][(t & ~63)*8]);

#pragma unroll
        for (int jt = 0; jt < 4; ++jt) {
            const __bf16* kb = &Ks[cur][(jt*16 + fr)*64];
            bf16x8 af0 = ld8(kb + ((fq    ) ^ (fr & 7))*8);
            bf16x8 af1 = ld8(kb + ((fq + 4) ^ (fr & 7))*8);
#pragma unroll
            for (int it = 0; it < 2; ++it) {
                f32x4 s = MFMA16(af0, qf[it][0], lg[jt]);   // C-init = -log2 L
                s = MFMA16(af1, qf[it][1], s);
                bf16x4 pv;
#pragma unroll
                for (int r = 0; r < 4; ++r)
                    pv[r] = (__bf16)__builtin_amdgcn_exp2f(s[r]);
                int il = it*16 + fr;
                *(bf16x4*)&Pl[w][il*64 + (((jt*4 + fq) ^ (2*(fr & 7))))*4] = pv;
            }
        }

#pragma unroll
        for (int u = 0; u < 4; ++u) {
            int d = dq*4 + u;
            int f = (d ^ dq) & 7;
            *(bf16x2*)&Vs[cur][d*64 + (((jp >> 2) ^ f))*8 + (jp & 3)*2] =
                (bf16x2){ v0[u], v1[u] };
        }
        __syncthreads();

        __builtin_amdgcn_s_setprio(1);
#pragma unroll
        for (int kh = 0; kh < 2; ++kh) {
            bf16x8 pa0 = ld8(&Pl[w][(     fr)*64 + (((fq + 4*kh) ^ (fr & 7)))*8]);
            bf16x8 pa1 = ld8(&Pl[w][(16 + fr)*64 + (((fq + 4*kh) ^ (fr & 7)))*8]);
#pragma unroll
            for (int dt = 0; dt < 4; ++dt) {
                int d = dt*16 + fr;
                int f = (d ^ (d >> 2)) & 7;
                bf16x8 vb = ld8(&Vs[cur][d*64 + (((kh*4 + fq) ^ f))*8]);
                acc[0][dt] = MFMA16(pa0, vb, acc[0][dt]);
                acc[1][dt] = MFMA16(pa1, vb, acc[1][dt]);
            }
        }
        __builtin_amdgcn_s_setprio(0);
    }

    const int b = bh >> 4, h = bh & 15;
#pragma unroll
    for (int it = 0; it < 2; ++it)
#pragma unroll
        for (int dt = 0; dt < 4; ++dt)
#pragma unroll
            for (int r = 0; r < 4; ++r) {
                int i = iw + it*16 + fq*4 + r;
                X[((size_t)b*S_ + i)*D_ + h*DK_ + dt*16 + fr] =
                    (__bf16)acc[it][dt][r];
            }
}

// ---------------------------------------------------------------------------
// Host launcher
// ---------------------------------------------------------------------------
extern "C" void kernel_launch(void* const* d_in, const int* in_sizes, int n_in,
                              void* d_out, int out_size, void* d_ws, size_t ws_size,
                              hipStream_t stream)
{
    const float* query = (const float*)d_in[0];
    const float* key   = (const float*)d_in[1];
    const float* value = (const float*)d_in[2];
    const float* Wq = (const float*)d_in[3];  const float* bq = (const float*)d_in[4];
    const float* Wk = (const float*)d_in[5];  const float* bk = (const float*)d_in[6];
    const float* Wv = (const float*)d_in[7];  const float* bv = (const float*)d_in[8];
    const float* Wo = (const float*)d_in[9];  const float* bo = (const float*)d_in[10];

    char* ws = (char*)d_ws;
    char* dob = (char*)d_out;
    const size_t MiB = 1024 * 1024;
    __bf16* Qb = (__bf16*)(ws);              // [B,H,S,Dk] 16 MiB
    __bf16* Kb = (__bf16*)(ws + 16 * MiB);
    __bf16* Vb = (__bf16*)(ws + 32 * MiB);
    __bf16* Xb = (__bf16*)(ws + 48 * MiB);   // [B,S,D]
    float*  Lgb = (float*)d_out;             // 512 KiB @ d_out+0 (-log2 L)
    __bf16* Wt3 = (__bf16*)(dob + 1 * MiB);  // WtQ|WtK|WtV, 2 MiB each
    __bf16* WtO = (__bf16*)(ws);             // Qb region, reused after attn_pv

    // weights -> W^T bf16 (scratch in d_out; dead until final GEMM)
    wtrans3<<<dim3(16,16,3), 256, 0, stream>>>(Wq, Wk, Wv, Wt3);

    // batched Q/K/V projections (Q scaled by SC2_), counted-vmcnt pipeline
    gemm_proj3<<<1536, 256, 0, stream>>>(query, key, value, Wt3,
                                         bq, bk, bv, Qb, Kb, Vb);

    colsum_rcp<<<2048, 256, 0, stream>>>(Qb, Kb, Lgb);

    attn_pv<<<512, 512, 0, stream>>>(Qb, Kb, Vb, Lgb, Xb);

    // Wo^T into Qb region (dead now); then final GEMM reads it from ws
    wtrans3<<<dim3(16,16,1), 256, 0, stream>>>(Wo, Wo, Wo, WtO);

    gemm128<1,0><<<512, 256, 0, stream>>>(Xb, WtO, bo, d_out, 1.0f);
}